// Round 7
// baseline (79.447 us; speedup 1.0000x reference)
//
#include <hip/hip_runtime.h>

#define NB   256        // bins per batch (power of two, == TPB)
#define TPB  256
#define NI   (NB + 1)   // intervals around/between sorted bins
#define G    128        // chunks per batch -> 512 blocks = 2/CU
#define MINF 1e30f
#define CAPD 1e15f      // cap so d*d == 1e30 == reference BIG when a side is empty

// Single fused kernel. Cross-block dataflow rules:
//  - everything other blocks must see is written with DEVICE-SCOPE ATOMICS
//    (performed at the device coherence point -> visible without release fences)
//  - __syncthreads() drains each wave's vmcnt before s_barrier, so the signal
//    atomicAdd is ordered after all data atomics (no per-block __threadfence,
//    which was the r3 pathology)
//  - only the single finalizing block pays one __threadfence() (acquire) before
//    plain-loading the published state
__global__ __launch_bounds__(TPB) void k_fused(
    const float* __restrict__ bc, const float* __restrict__ gt,
    int B, int V, int CH,
    unsigned* __restrict__ gbin,     // [B*NB] min d^2 bits (atomicMin; memset 0xFF)
    unsigned* __restrict__ counter,  // [1]    completion counter (memset 0xFF)
    unsigned* __restrict__ ssort,    // [B*NB] sorted-bin bits (atomicExch, write-once)
    unsigned* __restrict__ sumP,     // [B*G]  per-block dir-1 sum bits (atomicExch)
    unsigned* __restrict__ cntP,     // [B*G]  per-block valid count (atomicExch)
    float* __restrict__ out)
{
    const int b   = blockIdx.x / G;
    const int blk = blockIdx.x % G;
    const int tid = threadIdx.x;

    __shared__ float    c[NB];
    __shared__ unsigned imn[NI], imx[NI];
    __shared__ float    pm[NB], sm[NB];
    __shared__ float r4[4]; __shared__ int i4[4]; __shared__ float q4[4];
    __shared__ float ssa[8]; __shared__ int sn[8];
    __shared__ unsigned s_old;

    c[tid] = bc[b * NB + tid];
    for (int t = tid; t < NI; t += TPB) { imn[t] = 0xFFFFFFFFu; imx[t] = 0u; }
    __syncthreads();

    // ---- bitonic sort the 256 bins (redundant per block; ~1-2 us, overlapped) ----
    for (int k = 2; k <= NB; k <<= 1)
        for (int j = k >> 1; j > 0; j >>= 1) {
            const int ixj = tid ^ j;
            if (ixj > tid) {
                const float a = c[tid], bv = c[ixj];
                if ((a > bv) == ((tid & k) == 0)) { c[tid] = bv; c[ixj] = a; }
            }
            __syncthreads();
        }

    // publish sorted bins once per batch (write-once slot, needs no init)
    if (blk == 0) atomicExch(&ssort[b * NB + tid], __float_as_uint(c[tid]));

    // ---- stream this chunk's points: dir-1 + per-interval min/max ----
    const int start = blk * CH;
    const int cn = min(CH, V - start);
    const float* __restrict__ gp = gt + (size_t)b * V + start;
    float sum = 0.f; int cnt = 0;
    for (int i = tid; i < cn; i += TPB) {
        const float q = gp[i];
        if (q >= 0.001f) {
            // branchless lower-bound: idx = #bins <= q, in [0,256]
            int idx = 0;
            #pragma unroll
            for (int st = 128; st >= 1; st >>= 1)
                idx += (c[idx + st - 1] <= q) ? st : 0;
            idx += (c[idx] <= q) ? 1 : 0;
            const float dlo = (idx > 0)  ? (q - c[idx - 1]) : MINF;
            const float dhi = (idx < NB) ? (c[idx] - q)     : MINF;
            const float d = fminf(dlo, dhi);
            sum += d * d; ++cnt;
            // nonneg float bits order as uints -> exact LDS min/max
            atomicMin(&imn[idx], __float_as_uint(q));
            atomicMax(&imx[idx], __float_as_uint(q));
        }
    }
    __syncthreads();

    // ---- local fused scan: prefix-max of interval maxima / suffix-min of minima ----
    pm[tid] = (imx[tid]     == 0u)          ? -MINF : __uint_as_float(imx[tid]);
    sm[tid] = (imn[tid + 1] == 0xFFFFFFFFu) ?  MINF : __uint_as_float(imn[tid + 1]);
    __syncthreads();
    for (int off = 1; off < NB; off <<= 1) {
        const float vp = pm[tid], vs = sm[tid];
        const float op = (tid >= off)     ? pm[tid - off] : -MINF;
        const float os = (tid + off < NB) ? sm[tid + off] :  MINF;
        __syncthreads();
        pm[tid] = fmaxf(vp, op);
        sm[tid] = fminf(vs, os);
        __syncthreads();
    }
    // per-bin candidate from THIS chunk; min over blocks == global min (monotone)
    {
        const float cj = c[tid];
        const float d  = fminf(fminf(cj - pm[tid], sm[tid] - cj), CAPD);
        atomicMin(&gbin[b * NB + tid], __float_as_uint(d * d));
    }

    // ---- deterministic block reduce of dir-1 sum + count -> write-once slots ----
    for (int off = 32; off; off >>= 1) {
        sum += __shfl_down(sum, off);
        cnt += __shfl_down(cnt, off);
    }
    if ((tid & 63) == 0) { r4[tid >> 6] = sum; i4[tid >> 6] = cnt; }
    __syncthreads();
    if (tid == 0) {
        atomicExch(&sumP[blockIdx.x], __float_as_uint(r4[0] + r4[1] + r4[2] + r4[3]));
        atomicExch(&cntP[blockIdx.x], (unsigned)(i4[0] + i4[1] + i4[2] + i4[3]));
    }

    // ---- signal (syncthreads' vmcnt drain orders it after the data atomics) ----
    __syncthreads();
    if (tid == 0) s_old = atomicAdd(counter, 1u);
    __syncthreads();
    // counter init 0xFFFFFFFF: old values run -1,0,...,grid-2 -> last sees grid-2
    if (s_old != (unsigned)(gridDim.x - 2)) return;
    __threadfence();   // single acquire: invalidate stale L1/L2, then plain-load

    // ---- finalize (structure identical to r6 k_final -> bit-exact result) ----
    for (int bb = 0; bb < B; ++bb) {
        float s = 0.f; int cc = 0;
        for (int k = tid; k < G; k += TPB) {
            s  += __uint_as_float(sumP[bb * G + k]);
            cc += (int)cntP[bb * G + k];
        }
        for (int off = 32; off; off >>= 1) { s += __shfl_down(s, off); cc += __shfl_down(cc, off); }
        if ((tid & 63) == 0) { r4[tid >> 6] = s; i4[tid >> 6] = cc; }
        __syncthreads();
        if (tid == 0) { ssa[bb] = r4[0]+r4[1]+r4[2]+r4[3]; sn[bb] = i4[0]+i4[1]+i4[2]+i4[3]; }
        __syncthreads();
    }
    int Lmax = 0;
    for (int bb = 0; bb < B; ++bb) Lmax = max(Lmax, sn[bb]);

    float total = 0.f;
    for (int bb = 0; bb < B; ++bb) {
        const int   npad = Lmax - sn[bb];
        const float cj = __uint_as_float(ssort[bb * NB + tid]);
        const float c2 = cj * cj;
        float bm = __uint_as_float(gbin[bb * NB + tid]);   // 1e30 (BIG) if no points
        if (npad > 0) bm = fminf(bm, c2);   // pad points sit at 0 -> dist c^2
        float s = bm, mc = c2;
        for (int off = 32; off; off >>= 1) {
            s  += __shfl_down(s, off);
            mc  = fminf(mc, __shfl_down(mc, off));
        }
        if ((tid & 63) == 0) { r4[tid >> 6] = s; q4[tid >> 6] = mc; }
        __syncthreads();
        if (tid == 0)
            total += ssa[bb]
                   + (float)npad * fminf(fminf(q4[0], q4[1]), fminf(q4[2], q4[3]))
                   + (r4[0] + r4[1] + r4[2] + r4[3]);
        __syncthreads();
    }
    if (tid == 0) out[0] = total / (float)B;   // batch_reduction = mean
}

extern "C" void kernel_launch(void* const* d_in, const int* in_sizes, int n_in,
                              void* d_out, int out_size, void* d_ws, size_t ws_size,
                              hipStream_t stream) {
    const float* bc = (const float*)d_in[0];   // [B, 256, 1]
    const float* gt = (const float*)d_in[1];   // [B, 1, H, W]
    const int B  = in_sizes[0] / NB;           // 4
    const int V  = in_sizes[1] / B;            // 157696 = 128 * 1232
    const int CH = (V + G - 1) / G;            // 1232

    unsigned* gbin    = (unsigned*)d_ws;               // [B*NB]
    unsigned* counter = gbin + (size_t)B * NB;         // [1]  (adjacent: one memset)
    unsigned* ssort   = counter + 1;                   // [B*NB] write-once, no init
    unsigned* sumP    = ssort + (size_t)B * NB;        // [B*G]  write-once, no init
    unsigned* cntP    = sumP + (size_t)B * G;          // [B*G]  write-once, no init

    // 4 KB fill: gbin = 0xFFFFFFFF (identity for uint atomicMin on nonneg float
    // bits) and counter = 0xFFFFFFFF (kernel expects old==grid-2 at the end).
    // Dispatch-boundary release/acquire makes it visible to k_fused's atomics.
    hipMemsetAsync(gbin, 0xFF, ((size_t)B * NB + 1) * sizeof(unsigned), stream);

    k_fused<<<B * G, TPB, 0, stream>>>(bc, gt, B, V, CH,
                                       gbin, counter, ssort, sumP, cntP,
                                       (float*)d_out);
}